// Round 1
// baseline (458.146 us; speedup 1.0000x reference)
//
#include <hip/hip_runtime.h>
#include <hip/hip_bf16.h>

// Problem constants (fixed by setup_inputs)
constexpr int BB = 2;        // batch
constexpr int CC = 128;      // channels
constexpr int NN = 65536;    // H*W pixels
constexpr int MM = 1024;     // N / chunks
constexpr int LASTOFF = 63 * 1024;  // (chunks-1)*M : pixel offset of last chunk
constexpr float INV_T = 1.0f / 0.07f;
constexpr float L2E = 1.44269504088896340736f;  // log2(e)

typedef float f32x4 __attribute__((ext_vector_type(4)));
typedef short bf16x8 __attribute__((ext_vector_type(8)));

// ---------------------------------------------------------------------------
// K1: per-pixel norms + positive logit.
// thread = one (b,p) pixel; loops c with coalesced reads (consecutive p).
__global__ __launch_bounds__(256) void k_norms(
    const float* __restrict__ z1, const float* __restrict__ z2,
    float* __restrict__ inv1, float* __restrict__ inv2,
    float* __restrict__ posv) {
  int idx = blockIdx.x * 256 + threadIdx.x;  // 0 .. B*N-1
  int b = idx >> 16;                         // N = 65536
  int p = idx & (NN - 1);
  const float* a = z1 + (size_t)b * CC * NN + p;
  const float* c2 = z2 + (size_t)b * CC * NN + p;
  float s11 = 0.f, s22 = 0.f, s12 = 0.f;
#pragma unroll 8
  for (int c = 0; c < CC; c++) {
    float x = a[(size_t)c * NN];
    float y = c2[(size_t)c * NN];
    s11 += x * x;
    s22 += y * y;
    s12 += x * y;
  }
  float i1 = 1.0f / fmaxf(sqrtf(s11), 1e-12f);
  float i2 = 1.0f / fmaxf(sqrtf(s22), 1e-12f);
  inv1[idx] = i1;
  inv2[idx] = i2;
  posv[idx] = s12 * i1 * i2 * INV_T;
}

// ---------------------------------------------------------------------------
// K2: transpose + normalize + cast to bf16.
// src is [b][c][N] (channel-major); dst is [b][pixel][c] row-major bf16.
// Block: 64 pixels x 128 channels via LDS tile (pad 129 -> conflict-free).
__global__ __launch_bounds__(256) void k_tn(
    const float* __restrict__ src, const float* __restrict__ inv,
    __hip_bfloat16* __restrict__ dst, int p_offset, int dstP) {
  __shared__ float tile[64 * 129];
  __shared__ float inv_s[64];
  const int b = blockIdx.y;
  const int p0 = p_offset + blockIdx.x * 64;  // global pixel base
  const int t = threadIdx.x;
  const float* s = src + (size_t)b * CC * NN + p0;
  if (t < 64) inv_s[t] = inv[(size_t)b * NN + p0 + t];
#pragma unroll 8
  for (int e = 0; e < 32; e++) {
    int lin = e * 256 + t;
    int c = lin >> 6;   // 0..127
    int p = lin & 63;   // 0..63
    tile[p * 129 + c] = s[(size_t)c * NN + p];
  }
  __syncthreads();
  const size_t dbase = ((size_t)b * dstP + (size_t)blockIdx.x * 64) * CC;
#pragma unroll 8
  for (int e = 0; e < 32; e++) {
    int lin = e * 256 + t;
    int p = lin >> 7;    // 0..63
    int c = lin & 127;   // 0..127
    float v = tile[p * 129 + c] * inv_s[p];
    dst[dbase + (size_t)p * CC + c] = __float2bfloat16(v);
  }
}

// ---------------------------------------------------------------------------
// K3: fused GEMM (neg logits) + mask + online softmax row-reduction.
// Block: 16 pixel-rows, 4 waves; wave w covers cols [w*256, w*256+256).
// mfma_f32_16x16x32_bf16; C/D layout: col = lane&15, row = (lane>>4)*4 + reg.
__global__ __launch_bounds__(256) void k_gemm(
    const ushort* __restrict__ z1n,   // [b][N][C] bf16 bits
    const ushort* __restrict__ r2n,   // [b][M][C] bf16 bits
    const int* __restrict__ lab,      // [b][N]
    const float* __restrict__ posv,   // [b][N], already /T
    float* __restrict__ accum) {
  const int b = blockIdx.y;
  const int p0 = blockIdx.x * 16;
  const int tid = threadIdx.x;
  const int w = tid >> 6;
  const int lane = tid & 63;
  const int lrow = lane & 15;  // A-row / B-col within 16x16 tile
  const int kg = lane >> 4;    // k-group 0..3
  const int n0 = w * 256;

  const ushort* Ab = z1n + ((size_t)b * NN + p0 + lrow) * CC + kg * 8;
  const ushort* Bb = r2n + ((size_t)b * MM + n0 + lrow) * CC + kg * 8;

  bf16x8 av[4];
#pragma unroll
  for (int kk = 0; kk < 4; kk++)
    av[kk] = *reinterpret_cast<const bf16x8*>(Ab + kk * 32);

  f32x4 acc[16];
#pragma unroll
  for (int t = 0; t < 16; t++) acc[t] = f32x4{0.f, 0.f, 0.f, 0.f};

#pragma unroll
  for (int t = 0; t < 16; t++) {
    const ushort* Bt = Bb + (size_t)t * 16 * CC;
#pragma unroll
    for (int kk = 0; kk < 4; kk++) {
      bf16x8 bv = *reinterpret_cast<const bf16x8*>(Bt + kk * 32);
      acc[t] = __builtin_amdgcn_mfma_f32_16x16x32_bf16(av[kk], bv, acc[t], 0, 0, 0);
    }
  }

  // labels for masking
  int rl[4];
#pragma unroll
  for (int i = 0; i < 4; i++) rl[i] = lab[(size_t)b * NN + p0 + kg * 4 + i];
  int cl[16];
#pragma unroll
  for (int t = 0; t < 16; t++)
    cl[t] = lab[(size_t)b * NN + LASTOFF + n0 + t * 16 + lrow];

  __shared__ float sm[4][16], ss[4][16], sx[4][16];

#pragma unroll
  for (int i = 0; i < 4; i++) {
    float xv[16];
    float m = -1e30f, xs = 0.f;
#pragma unroll
    for (int t = 0; t < 16; t++) {
      float x = (rl[i] != cl[t]) ? acc[t][i] * INV_T : 0.0f;
      xv[t] = x;
      m = fmaxf(m, x);
      xs += x;
    }
    float s = 0.f;
#pragma unroll
    for (int t = 0; t < 16; t++) s += exp2f((xv[t] - m) * L2E);
    // reduce (m,s,xs) across the 16 lanes sharing this row set
#pragma unroll
    for (int d = 1; d < 16; d <<= 1) {
      float mo = __shfl_xor(m, d);
      float so = __shfl_xor(s, d);
      float xo = __shfl_xor(xs, d);
      float M2 = fmaxf(m, mo);
      s = s * exp2f((m - M2) * L2E) + so * exp2f((mo - M2) * L2E);
      m = M2;
      xs += xo;
    }
    if (lrow == 0) {
      int r = kg * 4 + i;
      sm[w][r] = m;
      ss[w][r] = s;
      sx[w][r] = xs;
    }
  }
  __syncthreads();

  float rowv = 0.f;
  if (tid < 16) {
    float m = sm[0][tid], s = ss[0][tid], xs = sx[0][tid];
#pragma unroll
    for (int wv = 1; wv < 4; wv++) {
      float mo = sm[wv][tid], so = ss[wv][tid], xo = sx[wv][tid];
      float M2 = fmaxf(m, mo);
      s = s * exp2f((m - M2) * L2E) + so * exp2f((mo - M2) * L2E);
      m = M2;
      xs += xo;
    }
    // add the positive logit (never masked)
    float pv = posv[(size_t)b * NN + p0 + tid];
    float M2 = fmaxf(m, pv);
    s = s * exp2f((m - M2) * L2E) + exp2f((pv - M2) * L2E);
    xs += pv;
    float lse = M2 + __logf(s);
    rowv = 1025.0f * lse - xs;  // (M+1)*lse - sum(logits) for this row
  }
  if (tid < 64) {
#pragma unroll
    for (int d = 1; d < 64; d <<= 1) rowv += __shfl_xor(rowv, d);
    if (tid == 0) atomicAdd(accum, rowv);
  }
}

// ---------------------------------------------------------------------------
__global__ void k_final(const float* __restrict__ accum, float* __restrict__ out) {
  // count = B*chunks*M*(M+1) = 2*64*1024*1025 = 134348800
  out[0] = accum[0] * (1.0f / 134348800.0f);
}

// ---------------------------------------------------------------------------
extern "C" void kernel_launch(void* const* d_in, const int* in_sizes, int n_in,
                              void* d_out, int out_size, void* d_ws, size_t ws_size,
                              hipStream_t stream) {
  const float* z1 = (const float*)d_in[0];
  const float* z2 = (const float*)d_in[1];
  const int* lab = (const int*)d_in[2];

  char* ws = (char*)d_ws;
  ushort* z1n = (ushort*)ws;                       // B*N*C bf16 = 33,554,432 B
  ushort* r2n = (ushort*)(ws + 33554432);          // B*M*C bf16 =    524,288 B
  float* inv1 = (float*)(ws + 34078720);           // B*N f32    =    524,288 B
  float* inv2 = (float*)(ws + 34603008);           //                 524,288 B
  float* posv = (float*)(ws + 35127296);           //                 524,288 B
  float* accum = (float*)(ws + 35651584);          //                       4 B

  hipMemsetAsync(accum, 0, sizeof(float), stream);

  k_norms<<<dim3(BB * NN / 256), 256, 0, stream>>>(z1, z2, inv1, inv2, posv);
  k_tn<<<dim3(NN / 64, BB), 256, 0, stream>>>(z1, inv1, (__hip_bfloat16*)z1n, 0, NN);
  k_tn<<<dim3(MM / 64, BB), 256, 0, stream>>>(z2, inv2, (__hip_bfloat16*)r2n, LASTOFF, MM);
  k_gemm<<<dim3(NN / 16, BB), 256, 0, stream>>>(z1n, r2n, lab, posv, accum);
  k_final<<<1, 1, 0, stream>>>(accum, (float*)d_out);
}

// Round 2
// 256.114 us; speedup vs baseline: 1.7888x; 1.7888x over previous
//
#include <hip/hip_runtime.h>
#include <hip/hip_bf16.h>

constexpr int BB = 2;        // batch
constexpr int CC = 128;      // channels
constexpr int NN = 65536;    // H*W pixels
constexpr int MM = 1024;     // N / chunks
constexpr int LASTOFF = 63 * 1024;   // pixel offset of last chunk
constexpr float INV_T = 1.0f / 0.07f;
constexpr float L2E = 1.44269504088896340736f;  // log2(e)
constexpr float C2 = INV_T * L2E;               // logits pre-scaled to base-2 domain
// loss = accum / (count * L2E); count = B*chunks*M*(M+1) = 134348800
constexpr float SCALE = 1.0f / (134348800.0f * 1.44269504088896340736f);

typedef float f32x4 __attribute__((ext_vector_type(4)));
typedef short bf16x8 __attribute__((ext_vector_type(8)));

__device__ __forceinline__ uint pack_bf16(float a, float b) {
  __hip_bfloat16 ha = __float2bfloat16(a);
  __hip_bfloat16 hb = __float2bfloat16(b);
  ushort ua = *reinterpret_cast<ushort*>(&ha);
  ushort ub = *reinterpret_cast<ushort*>(&hb);
  return (uint)ua | ((uint)ub << 16);
}

// ---------------------------------------------------------------------------
// K1: fused norms + positive logit + transpose + bf16 cast for z1.
// Block = 64 pixels, 256 threads = 8 channel-groups x 32 pixel-pairs.
// Norm partial sums accumulate in registers DURING the load; cross-group
// combine via small LDS arrays. Then transposed bf16 write from the LDS tile.
__global__ __launch_bounds__(256) void k_prep(
    const float* __restrict__ z1, const float* __restrict__ z2,
    uint* __restrict__ z1n, float* __restrict__ posv) {
  __shared__ float t1[64 * 129];
  __shared__ float part[3][8][65];
  __shared__ float inv1s[64];
  const int b = blockIdx.y;
  const int p0 = blockIdx.x * 64;
  const int t = threadIdx.x;
  const int p2 = t & 31;   // pixel pair: pixels 2*p2, 2*p2+1
  const int q = t >> 5;    // channel group 0..7
  const float* s1 = z1 + (size_t)b * CC * NN + p0 + 2 * p2;
  const float* s2 = z2 + (size_t)b * CC * NN + p0 + 2 * p2;
  float a11 = 0.f, a22 = 0.f, a12 = 0.f;   // pixel 2p2
  float b11 = 0.f, b22 = 0.f, b12 = 0.f;   // pixel 2p2+1
#pragma unroll
  for (int e = 0; e < 16; e++) {
    int c = e * 8 + q;
    float2 x = *reinterpret_cast<const float2*>(s1 + (size_t)c * NN);
    float2 y = *reinterpret_cast<const float2*>(s2 + (size_t)c * NN);
    t1[(2 * p2) * 129 + c] = x.x;
    t1[(2 * p2 + 1) * 129 + c] = x.y;
    a11 += x.x * x.x; a22 += y.x * y.x; a12 += x.x * y.x;
    b11 += x.y * x.y; b22 += y.y * y.y; b12 += x.y * y.y;
  }
  part[0][q][2 * p2] = a11; part[0][q][2 * p2 + 1] = b11;
  part[1][q][2 * p2] = a22; part[1][q][2 * p2 + 1] = b22;
  part[2][q][2 * p2] = a12; part[2][q][2 * p2 + 1] = b12;
  __syncthreads();
  if (t < 64) {
    float s11 = 0.f, s22 = 0.f, s12 = 0.f;
#pragma unroll
    for (int qq = 0; qq < 8; qq++) {
      s11 += part[0][qq][t];
      s22 += part[1][qq][t];
      s12 += part[2][qq][t];
    }
    float i1 = 1.0f / fmaxf(sqrtf(s11), 1e-12f);
    float i2 = 1.0f / fmaxf(sqrtf(s22), 1e-12f);
    inv1s[t] = i1;
    posv[(size_t)b * NN + p0 + t] = s12 * i1 * i2 * INV_T;
  }
  __syncthreads();
  const size_t obase = ((size_t)b * NN + p0) * 64;  // uint units (2 ch / uint)
#pragma unroll
  for (int e = 0; e < 16; e++) {
    int lin = e * 256 + t;
    int pp = lin >> 6;
    int cp = lin & 63;
    float i1 = inv1s[pp];
    float v0 = t1[pp * 129 + 2 * cp] * i1;
    float v1 = t1[pp * 129 + 2 * cp + 1] * i1;
    z1n[obase + (size_t)pp * 64 + cp] = pack_bf16(v0, v1);
  }
}

// ---------------------------------------------------------------------------
// K2: normalize + transpose + bf16 for z2's last chunk only (2x16 blocks).
__global__ __launch_bounds__(256) void k_r2(
    const float* __restrict__ z2, uint* __restrict__ r2n) {
  __shared__ float t2[64 * 129];
  __shared__ float part[8][65];
  __shared__ float inv2s[64];
  const int b = blockIdx.y;
  const int pg = blockIdx.x * 64;          // within last chunk
  const int p0 = LASTOFF + pg;
  const int t = threadIdx.x;
  const int p2 = t & 31;
  const int q = t >> 5;
  const float* s2 = z2 + (size_t)b * CC * NN + p0 + 2 * p2;
  float a22 = 0.f, b22 = 0.f;
#pragma unroll
  for (int e = 0; e < 16; e++) {
    int c = e * 8 + q;
    float2 y = *reinterpret_cast<const float2*>(s2 + (size_t)c * NN);
    t2[(2 * p2) * 129 + c] = y.x;
    t2[(2 * p2 + 1) * 129 + c] = y.y;
    a22 += y.x * y.x;
    b22 += y.y * y.y;
  }
  part[q][2 * p2] = a22;
  part[q][2 * p2 + 1] = b22;
  __syncthreads();
  if (t < 64) {
    float s22 = 0.f;
#pragma unroll
    for (int qq = 0; qq < 8; qq++) s22 += part[qq][t];
    inv2s[t] = 1.0f / fmaxf(sqrtf(s22), 1e-12f);
  }
  __syncthreads();
  const size_t obase = ((size_t)b * MM + pg) * 64;
#pragma unroll
  for (int e = 0; e < 16; e++) {
    int lin = e * 256 + t;
    int pp = lin >> 6;
    int cp = lin & 63;
    float i2 = inv2s[pp];
    float v0 = t2[pp * 129 + 2 * cp] * i2;
    float v1 = t2[pp * 129 + 2 * cp + 1] * i2;
    r2n[obase + (size_t)pp * 64 + cp] = pack_bf16(v0, v1);
  }
}

// ---------------------------------------------------------------------------
// K3: fused GEMM + mask + softmax-sum reduction.
// 4 independent waves/block; each wave owns 64 rows x all 1024 cols.
// Loop over 16 col-chunks of 64: 16 B-loads feed 64 MFMA (4x reuse).
// No online max: |logit| <= ~14.3/ln2 in base-2 -> sum exp2 < 2e9, fp32-safe.
// C/D layout (m89-verified): col = lane&15, row = (lane>>4)*4 + reg.
__global__ __launch_bounds__(256, 2) void k_gemm(
    const ushort* __restrict__ z1n,   // [b][N][C] bf16
    const ushort* __restrict__ r2n,   // [b][M][C] bf16
    const int* __restrict__ lab,      // [b][N]
    const float* __restrict__ posv,   // [b][N], already /T (natural units)
    float* __restrict__ accum) {
  const int b = blockIdx.y;
  const int tid = threadIdx.x;
  const int w = tid >> 6;
  const int lane = tid & 63;
  const int r = lane & 15;
  const int kg = lane >> 4;
  const int wrow0 = blockIdx.x * 256 + w * 64;

  // A fragments: 4 row-groups x K=128, kept in registers for the whole kernel.
  const ushort* Abase = z1n + ((size_t)b * NN + wrow0) * CC;
  bf16x8 av[4][4];
#pragma unroll
  for (int g = 0; g < 4; g++)
#pragma unroll
    for (int kk = 0; kk < 4; kk++)
      av[g][kk] = *reinterpret_cast<const bf16x8*>(
          Abase + ((size_t)(g * 16 + r)) * CC + kg * 8 + kk * 32);

  // Row labels for this lane's 16 row-slots.
  int rl[16];
#pragma unroll
  for (int g = 0; g < 4; g++)
#pragma unroll
    for (int i = 0; i < 4; i++)
      rl[g * 4 + i] = lab[(size_t)b * NN + wrow0 + g * 16 + kg * 4 + i];

  float sAcc[16], xAcc[16];
#pragma unroll
  for (int s = 0; s < 16; s++) { sAcc[s] = 0.f; xAcc[s] = 0.f; }

  const ushort* Bbase = r2n + (size_t)b * MM * CC;
  const int* clbase = lab + (size_t)b * NN + LASTOFF;

#pragma unroll 1
  for (int ch = 0; ch < 16; ch++) {
    const int n0 = ch * 64;
    bf16x8 bv[4][4];
#pragma unroll
    for (int tt = 0; tt < 4; tt++)
#pragma unroll
      for (int kk = 0; kk < 4; kk++)
        bv[tt][kk] = *reinterpret_cast<const bf16x8*>(
            Bbase + ((size_t)(n0 + tt * 16 + r)) * CC + kg * 8 + kk * 32);
    int cl[4];
#pragma unroll
    for (int tt = 0; tt < 4; tt++)
      cl[tt] = clbase[n0 + tt * 16 + r];

    f32x4 acc[4][4];
#pragma unroll
    for (int g = 0; g < 4; g++)
#pragma unroll
      for (int tt = 0; tt < 4; tt++)
        acc[g][tt] = f32x4{0.f, 0.f, 0.f, 0.f};

#pragma unroll
    for (int kk = 0; kk < 4; kk++)
#pragma unroll
      for (int g = 0; g < 4; g++)
#pragma unroll
        for (int tt = 0; tt < 4; tt++)
          acc[g][tt] = __builtin_amdgcn_mfma_f32_16x16x32_bf16(
              av[g][kk], bv[tt][kk], acc[g][tt], 0, 0, 0);

    // masked accumulation: base-2 scaled logits; masked entries are 0
    // (exp2(0)=1 still counts in the softmax denominator, as in reference).
#pragma unroll
    for (int g = 0; g < 4; g++)
#pragma unroll
      for (int tt = 0; tt < 4; tt++)
#pragma unroll
        for (int i = 0; i < 4; i++) {
          float xm = acc[g][tt][i] * C2;
          float e = exp2f(xm);
          bool sel = (rl[g * 4 + i] != cl[tt]);
          sAcc[g * 4 + i] += sel ? e : 1.0f;
          xAcc[g * 4 + i] += sel ? xm : 0.0f;
        }
  }

  // reduce partial (s, x) across the 16 lanes (r dim) sharing each row
#pragma unroll
  for (int d = 1; d < 16; d <<= 1) {
#pragma unroll
    for (int s = 0; s < 16; s++) {
      sAcc[s] += __shfl_xor(sAcc[s], d);
      xAcc[s] += __shfl_xor(xAcc[s], d);
    }
  }

  float tv = 0.f;
  if (r == 0) {
#pragma unroll
    for (int g = 0; g < 4; g++)
#pragma unroll
      for (int i = 0; i < 4; i++) {
        int row = wrow0 + g * 16 + kg * 4 + i;
        float pv = posv[(size_t)b * NN + row] * L2E;
        float s = sAcc[g * 4 + i] + exp2f(pv);
        float x = xAcc[g * 4 + i] + pv;
        tv += 1025.0f * __log2f(s) - x;
      }
  }
  tv += __shfl_xor(tv, 16);
  tv += __shfl_xor(tv, 32);
  if (lane == 0) atomicAdd(accum, tv);
}

// ---------------------------------------------------------------------------
__global__ void k_final(const float* __restrict__ accum, float* __restrict__ out) {
  out[0] = accum[0] * SCALE;
}

// ---------------------------------------------------------------------------
extern "C" void kernel_launch(void* const* d_in, const int* in_sizes, int n_in,
                              void* d_out, int out_size, void* d_ws, size_t ws_size,
                              hipStream_t stream) {
  const float* z1 = (const float*)d_in[0];
  const float* z2 = (const float*)d_in[1];
  const int* lab = (const int*)d_in[2];

  char* ws = (char*)d_ws;
  uint* z1n = (uint*)ws;                     // B*N*C bf16 = 33,554,432 B
  uint* r2n = (uint*)(ws + 33554432);        // B*M*C bf16 =    524,288 B
  float* posv = (float*)(ws + 34078720);     // B*N f32    =    524,288 B
  float* accum = (float*)(ws + 34603008);    //                       4 B

  hipMemsetAsync(accum, 0, sizeof(float), stream);

  k_prep<<<dim3(NN / 64, BB), 256, 0, stream>>>(z1, z2, z1n, posv);
  k_r2<<<dim3(MM / 64, BB), 256, 0, stream>>>(z2, r2n);
  k_gemm<<<dim3(NN / 256, BB), 256, 0, stream>>>(
      (const ushort*)z1n, (const ushort*)r2n, lab, posv, accum);
  k_final<<<1, 1, 0, stream>>>(accum, (float*)d_out);
}

// Round 3
// 253.631 us; speedup vs baseline: 1.8064x; 1.0098x over previous
//
#include <hip/hip_runtime.h>
#include <hip/hip_bf16.h>

constexpr int BB = 2;        // batch
constexpr int CC = 128;      // channels
constexpr int NN = 65536;    // H*W pixels
constexpr int MM = 1024;     // N / chunks
constexpr int LASTOFF = 63 * 1024;   // pixel offset of last chunk
constexpr float INV_T = 1.0f / 0.07f;
constexpr float L2E = 1.44269504088896340736f;  // log2(e)
constexpr float C2 = INV_T * L2E;               // fold /T and ln->log2 into A side
// loss = accum_base2 / (count * L2E); count = B*chunks*M*(M+1) = 134348800
constexpr float SCALE = 1.0f / (134348800.0f * 1.44269504088896340736f);
constexpr float EPSN = 1e-12f;

typedef float f32x4 __attribute__((ext_vector_type(4)));
typedef short bf16x8 __attribute__((ext_vector_type(8)));

__device__ __forceinline__ uint pack_bf16(float a, float b) {
  __hip_bfloat16 ha = __float2bfloat16(a);
  __hip_bfloat16 hb = __float2bfloat16(b);
  ushort ua = *reinterpret_cast<ushort*>(&ha);
  ushort ub = *reinterpret_cast<ushort*>(&hb);
  return (uint)ua | ((uint)ub << 16);
}

// ---------------------------------------------------------------------------
// K1: streaming per-pixel norms + positive logit. No LDS, register-only.
// Block = 512 pixels (thread = 2 px via float2), loops all 128 channels.
__global__ __launch_bounds__(256) void k_pos(
    const float* __restrict__ z1, const float* __restrict__ z2,
    float* __restrict__ i1c2, float* __restrict__ posv) {
  const int b = blockIdx.y;
  const int px = blockIdx.x * 512 + 2 * threadIdx.x;
  const float* p1 = z1 + (size_t)b * CC * NN + px;
  const float* p2 = z2 + (size_t)b * CC * NN + px;
  float s11a = 0.f, s22a = 0.f, s12a = 0.f;
  float s11b = 0.f, s22b = 0.f, s12b = 0.f;
#pragma unroll 8
  for (int c = 0; c < CC; c++) {
    float2 x = *reinterpret_cast<const float2*>(p1 + (size_t)c * NN);
    float2 y = *reinterpret_cast<const float2*>(p2 + (size_t)c * NN);
    s11a += x.x * x.x; s22a += y.x * y.x; s12a += x.x * y.x;
    s11b += x.y * x.y; s22b += y.y * y.y; s12b += x.y * y.y;
  }
  float i1a = 1.0f / fmaxf(sqrtf(s11a), EPSN);
  float i2a = 1.0f / fmaxf(sqrtf(s22a), EPSN);
  float i1b = 1.0f / fmaxf(sqrtf(s11b), EPSN);
  float i2b = 1.0f / fmaxf(sqrtf(s22b), EPSN);
  float2 iv = {i1a * C2, i1b * C2};
  float2 pv = {s12a * i1a * i2a * C2, s12b * i1b * i2b * C2};
  *reinterpret_cast<float2*>(i1c2 + (size_t)b * NN + px) = iv;
  *reinterpret_cast<float2*>(posv + (size_t)b * NN + px) = pv;
}

// ---------------------------------------------------------------------------
// K2: normalize + transpose + bf16 for z2's last chunk (B side, UNSCALED)
//     + per-label column-sum partials S_v = sum_{cl != v} col_n  (fp32 atomics).
__global__ __launch_bounds__(256) void k_r2(
    const float* __restrict__ z2, const int* __restrict__ lab,
    uint* __restrict__ r2n, float* __restrict__ Sv) {
  __shared__ float t2[64 * 129];
  __shared__ float part[8][65];
  __shared__ float inv2s[64];
  __shared__ int cls[64];
  const int b = blockIdx.y;
  const int pg = blockIdx.x * 64;          // within last chunk
  const int p0 = LASTOFF + pg;
  const int t = threadIdx.x;
  const int p2 = t & 31;
  const int q = t >> 5;
  const float* s2 = z2 + (size_t)b * CC * NN + p0 + 2 * p2;
  float a22 = 0.f, b22 = 0.f;
#pragma unroll
  for (int e = 0; e < 16; e++) {
    int c = e * 8 + q;
    float2 y = *reinterpret_cast<const float2*>(s2 + (size_t)c * NN);
    t2[(2 * p2) * 129 + c] = y.x;
    t2[(2 * p2 + 1) * 129 + c] = y.y;
    a22 += y.x * y.x;
    b22 += y.y * y.y;
  }
  part[q][2 * p2] = a22;
  part[q][2 * p2 + 1] = b22;
  __syncthreads();
  if (t < 64) {
    float s22 = 0.f;
#pragma unroll
    for (int qq = 0; qq < 8; qq++) s22 += part[qq][t];
    inv2s[t] = 1.0f / fmaxf(sqrtf(s22), EPSN);
    cls[t] = lab[(size_t)b * NN + p0 + t];
  }
  __syncthreads();
  const size_t obase = ((size_t)b * MM + pg) * 64;
#pragma unroll
  for (int e = 0; e < 16; e++) {
    int lin = e * 256 + t;
    int pp = lin >> 6;
    int cp = lin & 63;
    float i2 = inv2s[pp];
    float v0 = t2[pp * 129 + 2 * cp] * i2;
    float v1 = t2[pp * 129 + 2 * cp + 1] * i2;
    r2n[obase + (size_t)pp * 64 + cp] = pack_bf16(v0, v1);
  }
  // S_v partials: thread -> (channel c, pixel-half h)
  const int c = t & 127;
  const int h = t >> 7;
  float tot = 0.f, se0 = 0.f, se1 = 0.f, se2 = 0.f, se3 = 0.f, se4 = 0.f;
#pragma unroll
  for (int k = 0; k < 32; k++) {
    int pp = h * 32 + k;
    float val = t2[pp * 129 + c] * inv2s[pp];
    int lb = cls[pp];
    tot += val;
    se0 += (lb == 0) ? val : 0.f;
    se1 += (lb == 1) ? val : 0.f;
    se2 += (lb == 2) ? val : 0.f;
    se3 += (lb == 3) ? val : 0.f;
    se4 += (lb == 4) ? val : 0.f;
  }
  float* svb = Sv + b * 640 + c;
  atomicAdd(svb + 0 * 128, tot - se0);
  atomicAdd(svb + 1 * 128, tot - se1);
  atomicAdd(svb + 2 * 128, tot - se2);
  atomicAdd(svb + 3 * 128, tot - se3);
  atomicAdd(svb + 4 * 128, tot - se4);
}

// ---------------------------------------------------------------------------
// K3: pack S_v fp32 -> bf16 16-row extra B-tile (rows 5..15 zero).
__global__ void k_svpack(const float* __restrict__ Sv, ushort* __restrict__ r2x) {
  int i = blockIdx.x * 256 + threadIdx.x;  // 0..4095
  if (i >= BB * 16 * 128) return;
  int b = i >> 11, rr = (i >> 7) & 15, c = i & 127;
  float v = (rr < 5) ? Sv[b * 640 + rr * 128 + c] : 0.0f;
  __hip_bfloat16 h = __float2bfloat16(v);
  r2x[i] = *reinterpret_cast<ushort*>(&h);
}

// ---------------------------------------------------------------------------
// K4: fused {z1 normalize+transpose staging} + GEMM + mask + softmax-sum.
// Block = 256 px rows; stages A=[c][px] bf16 (pre-scaled by C2) in LDS from
// 1KB-contiguous z1 rows. 4 waves x 64 rows x all 1024 cols; B from L2.
// Per-row sum-of-logits comes from the 16-col S_v extra tile (x = dot(a,S_rl)).
// C/D layout: col = lane&15, row = (lane>>4)*4 + reg.
__global__ __launch_bounds__(256) void k_gemm(
    const float* __restrict__ z1, const float* __restrict__ i1c2,
    const ushort* __restrict__ r2n, const ushort* __restrict__ r2x,
    const int* __restrict__ lab, const float* __restrict__ posv,
    float* __restrict__ accum) {
  __shared__ ushort At[128 * 258];   // [c][px], pad 2 -> 66,048 B
  const int b = blockIdx.y;
  const int px0 = blockIdx.x * 256;
  const int tid = threadIdx.x;
  const int w = tid >> 6;
  const int lane = tid & 63;
  const int r = lane & 15;
  const int kg = lane >> 4;

  // --- stage A ---
  {
    const float* zb = z1 + (size_t)b * CC * NN + px0 + 4 * lane;
    f32x4 iv = *reinterpret_cast<const f32x4*>(i1c2 + (size_t)b * NN + px0 + 4 * lane);
#pragma unroll 4
    for (int e = 0; e < 32; e++) {
      int c = w * 32 + e;
      f32x4 v = *reinterpret_cast<const f32x4*>(zb + (size_t)c * NN);
      uint2 uu;
      uu.x = pack_bf16(v[0] * iv[0], v[1] * iv[1]);
      uu.y = pack_bf16(v[2] * iv[2], v[3] * iv[3]);
      *reinterpret_cast<uint2*>(&At[c * 258 + 4 * lane]) = uu;
    }
  }
  __syncthreads();

  const int wrow0 = w * 64;  // this wave's local row base
  // A fragments from LDS (one-time; 2-way banks = free)
  bf16x8 av[4][4];
#pragma unroll
  for (int g = 0; g < 4; g++)
#pragma unroll
    for (int kk = 0; kk < 4; kk++) {
      bf16x8 tv;
#pragma unroll
      for (int j = 0; j < 8; j++)
        tv[j] = (short)At[(kg * 8 + kk * 32 + j) * 258 + wrow0 + g * 16 + r];
      av[g][kk] = tv;
    }

  int rl[16];
#pragma unroll
  for (int g = 0; g < 4; g++)
#pragma unroll
    for (int i = 0; i < 4; i++)
      rl[g * 4 + i] = lab[(size_t)b * NN + px0 + wrow0 + g * 16 + kg * 4 + i];

  float sAcc[16];
#pragma unroll
  for (int s = 0; s < 16; s++) sAcc[s] = 0.f;

  const ushort* Bbase = r2n + (size_t)b * MM * CC;
  const int* clbase = lab + (size_t)b * NN + LASTOFF;

#pragma unroll 1
  for (int ch = 0; ch < 16; ch++) {
    const int n0 = ch * 64;
    bf16x8 bv[4][4];
#pragma unroll
    for (int tt = 0; tt < 4; tt++)
#pragma unroll
      for (int kk = 0; kk < 4; kk++)
        bv[tt][kk] = *reinterpret_cast<const bf16x8*>(
            Bbase + ((size_t)(n0 + tt * 16 + r)) * CC + kg * 8 + kk * 32);
    int cl[4];
#pragma unroll
    for (int tt = 0; tt < 4; tt++)
      cl[tt] = clbase[n0 + tt * 16 + r];

    f32x4 acc[4][4];
#pragma unroll
    for (int g = 0; g < 4; g++)
#pragma unroll
      for (int tt = 0; tt < 4; tt++)
        acc[g][tt] = f32x4{0.f, 0.f, 0.f, 0.f};

#pragma unroll
    for (int kk = 0; kk < 4; kk++)
#pragma unroll
      for (int g = 0; g < 4; g++)
#pragma unroll
        for (int tt = 0; tt < 4; tt++)
          acc[g][tt] = __builtin_amdgcn_mfma_f32_16x16x32_bf16(
              av[g][kk], bv[tt][kk], acc[g][tt], 0, 0, 0);

    // acc already = logit * C2 (A pre-scaled). Masked -> exp2(0)=1.
#pragma unroll
    for (int g = 0; g < 4; g++)
#pragma unroll
      for (int tt = 0; tt < 4; tt++)
#pragma unroll
        for (int i = 0; i < 4; i++) {
          float xm = (rl[g * 4 + i] != cl[tt]) ? acc[g][tt][i] : 0.0f;
          sAcc[g * 4 + i] += __builtin_amdgcn_exp2f(xm);
        }
  }

  // extra 16-col S_v tile: x_row = dot(a_scaled, S_v) = sum of unmasked logits*C2
  f32x4 accx[4];
  {
    bf16x8 bx[4];
#pragma unroll
    for (int kk = 0; kk < 4; kk++)
      bx[kk] = *reinterpret_cast<const bf16x8*>(
          r2x + (size_t)b * 16 * CC + (size_t)r * CC + kg * 8 + kk * 32);
#pragma unroll
    for (int g = 0; g < 4; g++) {
      accx[g] = f32x4{0.f, 0.f, 0.f, 0.f};
#pragma unroll
      for (int kk = 0; kk < 4; kk++)
        accx[g] = __builtin_amdgcn_mfma_f32_16x16x32_bf16(
            av[g][kk], bx[kk], accx[g], 0, 0, 0);
    }
  }

  // reduce sAcc across the 16 r-lanes sharing each row
#pragma unroll
  for (int d = 1; d < 16; d <<= 1)
#pragma unroll
    for (int s = 0; s < 16; s++) sAcc[s] += __shfl_xor(sAcc[s], d);

  // x select: value for (row, col=rl) lives in lane kg*16 + rl, reg i
  float xsel[16];
#pragma unroll
  for (int g = 0; g < 4; g++)
#pragma unroll
    for (int i = 0; i < 4; i++)
      xsel[g * 4 + i] = __shfl(accx[g][i], (lane & 48) | rl[g * 4 + i]);

  float tv = 0.f;
  if (r == 0) {
#pragma unroll
    for (int g = 0; g < 4; g++)
#pragma unroll
      for (int i = 0; i < 4; i++) {
        int row = px0 + wrow0 + g * 16 + kg * 4 + i;
        float pv = posv[(size_t)b * NN + row];   // already * C2
        float s = sAcc[g * 4 + i] + __builtin_amdgcn_exp2f(pv);
        float x = xsel[g * 4 + i] + pv;
        tv += 1025.0f * __log2f(s) - x;
      }
  }
  tv += __shfl_xor(tv, 16);
  tv += __shfl_xor(tv, 32);
  if (lane == 0) atomicAdd(accum, tv);
}

// ---------------------------------------------------------------------------
__global__ void k_scale(const float* __restrict__ accum, float* __restrict__ out) {
  out[0] = accum[0] * SCALE;
}

// ---------------------------------------------------------------------------
extern "C" void kernel_launch(void* const* d_in, const int* in_sizes, int n_in,
                              void* d_out, int out_size, void* d_ws, size_t ws_size,
                              hipStream_t stream) {
  const float* z1 = (const float*)d_in[0];
  const float* z2 = (const float*)d_in[1];
  const int* lab = (const int*)d_in[2];

  char* ws = (char*)d_ws;
  uint* r2n   = (uint*)ws;                      // B*M*C bf16  = 524,288 B
  ushort* r2x = (ushort*)(ws + 524288);         // B*16*C bf16 =   8,192 B
  float* posv = (float*)(ws + 532480);          // B*N f32     = 524,288 B
  float* i1c2 = (float*)(ws + 1056768);         // B*N f32     = 524,288 B
  float* Sv   = (float*)(ws + 1581056);         // B*5*128 f32 =   5,120 B
  float* accum = (float*)(ws + 1586176);        //                     4 B

  hipMemsetAsync(ws + 1581056, 0, 5124, stream);  // Sv + accum

  k_pos<<<dim3(NN / 512, BB), 256, 0, stream>>>(z1, z2, i1c2, posv);
  k_r2<<<dim3(MM / 64, BB), 256, 0, stream>>>(z2, lab, r2n, Sv);
  k_svpack<<<dim3(16), 256, 0, stream>>>(Sv, r2x);
  k_gemm<<<dim3(NN / 256, BB), 256, 0, stream>>>(
      z1, i1c2, (const ushort*)r2n, r2x, lab, posv, accum);
  k_scale<<<1, 1, 0, stream>>>(accum, (float*)d_out);
}